// Round 14
// baseline (2978.962 us; speedup 1.0000x reference)
//
#include <hip/hip_runtime.h>
#include <math.h>

#define NTOK 131072
#define HDIM 256
#define DDIM 512
#define FDIM 1024
#define EDIM 16
#define TBLK 128
#define FCH  128
#define KST  32
#define XST  40    // f16 row stride (80 B): 16B-aligned rows (b128-safe), 2-way-free reads
#define HST  68    // f32 row stride (272 B)

typedef __attribute__((ext_vector_type(8))) _Float16 v8h;
typedef __attribute__((ext_vector_type(4))) _Float16 v4h;
typedef __attribute__((ext_vector_type(4))) float v4f;

// f32 -> fp16 hi + lo residual (unscaled: residuals ~2^-11|v| are f16-normal).
// Total repr error <= 2^-22|v| + 2^-24.
__device__ __forceinline__ void f2h2(float v, _Float16& h, _Float16& l) {
    h = (_Float16)v;
    l = (_Float16)(v - (float)h);
}

// LDS 40960 B: xs_h[128][40] @0 (10240), xs_l @10240,
//              ws_h[128][40] @20480 (10240), ws_l @30720.
// GEMM2: hs f32 [128][68] = 34816 aliases @0, holds one 64-col half at a time.
// 256-thread/(256,2): only proven no-spill config (R1/R4/R9/R13 vs R2/R3/R10/R12).
__global__ __launch_bounds__(256, 2)
void router_mfma6(const float* __restrict__ inp,
                  const float* __restrict__ cnd,
                  const float* __restrict__ W1,
                  const float* __restrict__ b1,
                  const float* __restrict__ W2,
                  const float* __restrict__ b2,
                  float* __restrict__ out)
{
    __shared__ __align__(16) char smem[40960];
    _Float16* xs_h = (_Float16*)(smem);
    _Float16* xs_l = (_Float16*)(smem + 10240);
    _Float16* ws_h = (_Float16*)(smem + 20480);
    _Float16* ws_l = (_Float16*)(smem + 30720);
    float*    hs   = (float*)(smem);          // alias, barrier-separated

    const int tid  = threadIdx.x;
    const int lane = tid & 63;
    const int w    = tid >> 6;        // wave 0..3
    const int wr   = w >> 1;          // token half (64)
    const int wf   = w & 1;           // F half (64 of the 128-chunk)
    const int l15  = lane & 15;
    const int l4   = lane >> 4;
    const int t0   = blockIdx.x * TBLK;
    const int ty   = tid >> 4;        // 0..15: token group (8) for GEMM2/epilogue
    const int tx   = tid & 15;        // expert lane
    const int kq   = tid & 7;         // x staging: k-quad
    const int xr   = tid >> 3;        // x staging: base row (0..31)
    const int fcl  = tid & 127;       // W1 staging: F col
    const int kg   = tid >> 7;        // W1 staging: 0..1

    float lg[8];
    {
        const float bb = b2[tx];
#pragma unroll
        for (int i = 0; i < 8; ++i) lg[i] = bb;
    }

    for (int fc = 0; fc < FDIM; fc += FCH) {
        v4f acc[4][4];   // single accumulator for all 3 split terms
#pragma unroll
        for (int mf = 0; mf < 4; ++mf)
#pragma unroll
            for (int nf = 0; nf < 4; ++nf)
                acc[mf][nf] = (v4f){0.f,0.f,0.f,0.f};

        for (int st = 0; st < 16; ++st) {
            const int kc = st * KST;
            __syncthreads();   // prior MFMA reads done; st==0: prior GEMM2 hs reads done
            // ---- stage x tile [128 tok][32 k] as f16 hi/lo ----
            {
                const float* src = (kc < HDIM)
                    ? (inp + (size_t)t0 * HDIM + kc)
                    : (cnd + (size_t)t0 * HDIM + (kc - HDIM));
#pragma unroll
                for (int p = 0; p < 4; ++p) {
                    const int row = xr + 32 * p;
                    const float4 v = *(const float4*)(src + (size_t)row * HDIM + kq * 4);
                    _Float16 h0,l0,h1,l1,h2,l2,h3,l3;
                    f2h2(v.x,h0,l0); f2h2(v.y,h1,l1); f2h2(v.z,h2,l2); f2h2(v.w,h3,l3);
                    v4h hh, hl;
                    hh[0]=h0; hh[1]=h1; hh[2]=h2; hh[3]=h3;
                    hl[0]=l0; hl[1]=l1; hl[2]=l2; hl[3]=l3;
                    *(v4h*)(xs_h + row * XST + kq * 4) = hh;
                    *(v4h*)(xs_l + row * XST + kq * 4) = hl;
                }
            }
            // ---- stage W1 tile [32 k][128 F] -> ws[F][k] ----
#pragma unroll
            for (int s = 0; s < 4; ++s) {
                const int kb = 4 * (2 * s + kg);   // {0,4,...,28}
                const float u0 = W1[(size_t)(kc + kb + 0) * FDIM + fc + fcl];
                const float u1 = W1[(size_t)(kc + kb + 1) * FDIM + fc + fcl];
                const float u2 = W1[(size_t)(kc + kb + 2) * FDIM + fc + fcl];
                const float u3 = W1[(size_t)(kc + kb + 3) * FDIM + fc + fcl];
                _Float16 h0,l0,h1,l1,h2,l2,h3,l3;
                f2h2(u0,h0,l0); f2h2(u1,h1,l1); f2h2(u2,h2,l2); f2h2(u3,h3,l3);
                v4h hh, hl;
                hh[0]=h0; hh[1]=h1; hh[2]=h2; hh[3]=h3;
                hl[0]=l0; hl[1]=l1; hl[2]=l2; hl[3]=l3;
                *(v4h*)(ws_h + fcl * XST + kb) = hh;
                *(v4h*)(ws_l + fcl * XST + kb) = hl;
            }
            __syncthreads();
            // ---- MFMA 16x16x32 f16, 3 terms into ONE accumulator ----
            {
                v8h bh[4], bl[4];
#pragma unroll
                for (int nf = 0; nf < 4; ++nf) {
                    const int off = (64 * wf + 16 * nf + l15) * XST + 8 * l4;
                    bh[nf] = *(const v8h*)(ws_h + off);
                    bl[nf] = *(const v8h*)(ws_l + off);
                }
#pragma unroll
                for (int mf = 0; mf < 4; ++mf) {
                    const int off = (64 * wr + 16 * mf + l15) * XST + 8 * l4;
                    const v8h ah = *(const v8h*)(xs_h + off);
                    const v8h al = *(const v8h*)(xs_l + off);
#pragma unroll
                    for (int nf = 0; nf < 4; ++nf) {
                        acc[mf][nf] = __builtin_amdgcn_mfma_f32_16x16x32_f16(ah, bh[nf], acc[mf][nf], 0, 0, 0);
                        acc[mf][nf] = __builtin_amdgcn_mfma_f32_16x16x32_f16(al, bh[nf], acc[mf][nf], 0, 0, 0);
                        acc[mf][nf] = __builtin_amdgcn_mfma_f32_16x16x32_f16(ah, bl[nf], acc[mf][nf], 0, 0, 0);
                    }
                }
            }
        }
        __syncthreads();   // all MFMA xs/ws reads done; hs may alias them

        float b1v[4];
#pragma unroll
        for (int nf = 0; nf < 4; ++nf)
            b1v[nf] = b1[fc + 64 * wf + 16 * nf + l15];

#pragma unroll
        for (int h = 0; h < 2; ++h) {
            // ---- GELU: waves with wf==h write their 64 F cols (local 0..63) ----
            if (wf == h) {
#pragma unroll
                for (int mf = 0; mf < 4; ++mf)
#pragma unroll
                    for (int nf = 0; nf < 4; ++nf)
#pragma unroll
                        for (int r = 0; r < 4; ++r) {
                            const float v = acc[mf][nf][r] + b1v[nf];
                            const int tok  = 64 * wr + 16 * mf + 4 * l4 + r;
                            const int fcol = 16 * nf + l15;   // local 0..63
                            hs[tok * HST + fcol]
                                = 0.5f * v * (1.0f + erff(v * 0.70710678118654752f));
                        }
            }
            __syncthreads();
            // ---- GEMM2 half h: direct per-expert dot, jb staggered by l4 ----
            // bank(hs read) = 4*(i + jbs) mod 32; jbs differs by 4 per l4 ->
            // +16 banks -> 2-way (free). Per-thread order fixed -> deterministic.
#pragma unroll
            for (int jb = 0; jb < 16; ++jb) {
                const int jbs = (jb + 4 * l4) & 15;
                float w2v[4];
#pragma unroll
                for (int j = 0; j < 4; ++j)
                    w2v[j] = W2[(size_t)(fc + 64 * h + jbs * 4 + j) * EDIM + tx];
#pragma unroll
                for (int i = 0; i < 8; ++i) {
                    const float4 hv = *(const float4*)(hs + (ty * 8 + i) * HST + jbs * 4);
                    lg[i] = fmaf(hv.x, w2v[0], lg[i]);
                    lg[i] = fmaf(hv.y, w2v[1], lg[i]);
                    lg[i] = fmaf(hv.z, w2v[2], lg[i]);
                    lg[i] = fmaf(hv.w, w2v[3], lg[i]);
                }
            }
            if (h == 0) __syncthreads();   // half-1 GELU overwrites hs
        }
        // next fc pass's first staging barrier protects hs
    }

    // ---- softmax + clip + top-2 + writes (R4-proven 16-lane butterflies) ----
#pragma unroll
    for (int i = 0; i < 8; ++i) {
        const int t = t0 + ty * 8 + i;
        float mx = lg[i];
#pragma unroll
        for (int m = 1; m < 16; m <<= 1) mx = fmaxf(mx, __shfl_xor(mx, m, 64));
        float p = expf(lg[i] - mx);
        float s = p;
#pragma unroll
        for (int m = 1; m < 16; m <<= 1) s += __shfl_xor(s, m, 64);
        float pr = p / s;
        pr = fminf(fmaxf(pr, 1e-9f), 1.0f - 1e-9f);

        float v1 = pr; int i1 = tx;
#pragma unroll
        for (int m = 1; m < 16; m <<= 1) {
            const float vo = __shfl_xor(v1, m, 64);
            const int   io = __shfl_xor(i1, m, 64);
            if (vo > v1 || (vo == v1 && io < i1)) { v1 = vo; i1 = io; }
        }
        float v2 = (tx == i1) ? -1.0f : pr; int i2 = tx;
#pragma unroll
        for (int m = 1; m < 16; m <<= 1) {
            const float vo = __shfl_xor(v2, m, 64);
            const int   io = __shfl_xor(i2, m, 64);
            if (vo > v2 || (vo == v2 && io < i2)) { v2 = vo; i2 = io; }
        }
        const float rs = 1.0f / (v1 + v2);

        float* om  = out + (size_t)t * EDIM;
        float* orp = out + (size_t)NTOK * 18 + (size_t)t * EDIM;
        float* opf = out + (size_t)NTOK * 34 + (size_t)t * EDIM;
        om[tx]  = (tx == i1 || tx == i2) ? 1.0f : 0.0f;
        orp[tx] = (tx == i1) ? v1 * rs : ((tx == i2) ? v2 * rs : 0.0f);
        opf[tx] = pr;
        if (tx == 0) {
            float2* oi = (float2*)(out + (size_t)NTOK * 16 + (size_t)t * 2);
            *oi = make_float2((float)i1, (float)i2);
        }
    }
}

extern "C" void kernel_launch(void* const* d_in, const int* in_sizes, int n_in,
                              void* d_out, int out_size, void* d_ws, size_t ws_size,
                              hipStream_t stream)
{
    const float* inp = (const float*)d_in[0];
    const float* cnd = (const float*)d_in[1];
    const float* W1  = (const float*)d_in[2];
    const float* b1  = (const float*)d_in[3];
    const float* W2  = (const float*)d_in[4];
    const float* b2  = (const float*)d_in[5];
    float* out = (float*)d_out;

    dim3 grid(NTOK / TBLK), block(256);
    hipLaunchKernelGGL(router_mfma6, grid, block, 0, stream,
                       inp, cnd, W1, b1, W2, b2, out);
}

// Round 15
// 838.131 us; speedup vs baseline: 3.5543x; 3.5543x over previous
//
#include <hip/hip_runtime.h>
#include <math.h>

#define NTOK 131072
#define HDIM 256
#define DDIM 512
#define FDIM 1024
#define EDIM 16
#define TBLK 128
#define FCH  64
#define KST  32
#define XST  40    // f16 row stride (80 B, 16B-aligned)
#define HST  68    // f32 row stride (272 B, 16B-aligned)

typedef __attribute__((ext_vector_type(8))) _Float16 v8h;
typedef __attribute__((ext_vector_type(4))) _Float16 v4h;
typedef __attribute__((ext_vector_type(4))) float v4f;

// f32 -> fp16 hi + lo residual (unscaled — R14-validated: absmax 0.0039).
// Repr error <= 2^-22|v| + 2^-24 (residual may be subnormal; harmless).
__device__ __forceinline__ void f2h2(float v, _Float16& h, _Float16& l) {
    h = (_Float16)v;
    l = (_Float16)(v - (float)h);
}

// LDS 34816 B (4 blocks/CU):
//  staging: xs_h[128][40] @0 (10240), xs_l @10240,
//           ws_h[64][40] @20480 (5120), ws_l @25600  (total 30720)
//  GEMM2:   hs f32 [128][68] = 34816 aliases @0 (barrier-separated)
// (256,2) = the only proven no-spill config; empirical VGPR cap 128 — keep
// live set well under it (single 32-reg accumulator).
__global__ __launch_bounds__(256, 2)
void router_mfma7(const float* __restrict__ inp,
                  const float* __restrict__ cnd,
                  const float* __restrict__ W1,
                  const float* __restrict__ b1,
                  const float* __restrict__ W2,
                  const float* __restrict__ b2,
                  float* __restrict__ out)
{
    __shared__ __align__(16) char smem[34816];
    _Float16* xs_h = (_Float16*)(smem);
    _Float16* xs_l = (_Float16*)(smem + 10240);
    _Float16* ws_h = (_Float16*)(smem + 20480);
    _Float16* ws_l = (_Float16*)(smem + 25600);
    float*    hs   = (float*)(smem);          // alias, barrier-separated

    const int tid  = threadIdx.x;
    const int lane = tid & 63;
    const int w    = tid >> 6;        // wave 0..3
    const int wr   = w >> 1;          // token half (64)
    const int wc   = w & 1;           // F half (32 of the 64-chunk)
    const int l15  = lane & 15;
    const int l4   = lane >> 4;
    const int t0   = blockIdx.x * TBLK;
    const int ty   = tid >> 4;        // 0..15: token group (8) for GEMM2/epilogue
    const int tx   = tid & 15;        // expert lane
    const int kq   = tid & 7;         // x staging: k-quad
    const int xr   = tid >> 3;        // x staging: base row (0..31)
    const int fcl  = tid & 63;        // W1 staging: F col
    const int kg   = tid >> 6;        // W1 staging: 0..3

    float lg[8];
    {
        const float bb = b2[tx];
#pragma unroll
        for (int i = 0; i < 8; ++i) lg[i] = bb;
    }

    for (int fc = 0; fc < FDIM; fc += FCH) {
        v4f acc[4][2];   // single accumulator, all 3 split terms (R14-validated)
#pragma unroll
        for (int mf = 0; mf < 4; ++mf)
#pragma unroll
            for (int nf = 0; nf < 2; ++nf)
                acc[mf][nf] = (v4f){0.f,0.f,0.f,0.f};

        for (int st = 0; st < 16; ++st) {
            const int kc = st * KST;
            __syncthreads();   // prior MFMA reads / prior GEMM2 hs reads done
            // ---- stage x tile [128 tok][32 k] as f16 hi/lo ----
            {
                const float* src = (kc < HDIM)
                    ? (inp + (size_t)t0 * HDIM + kc)
                    : (cnd + (size_t)t0 * HDIM + (kc - HDIM));
#pragma unroll
                for (int p = 0; p < 4; ++p) {
                    const int row = xr + 32 * p;
                    const float4 v = *(const float4*)(src + (size_t)row * HDIM + kq * 4);
                    _Float16 h0,l0,h1,l1,h2,l2,h3,l3;
                    f2h2(v.x,h0,l0); f2h2(v.y,h1,l1); f2h2(v.z,h2,l2); f2h2(v.w,h3,l3);
                    v4h hh, hl;
                    hh[0]=h0; hh[1]=h1; hh[2]=h2; hh[3]=h3;
                    hl[0]=l0; hl[1]=l1; hl[2]=l2; hl[3]=l3;
                    *(v4h*)(xs_h + row * XST + kq * 4) = hh;
                    *(v4h*)(xs_l + row * XST + kq * 4) = hl;
                }
            }
            // ---- stage W1 tile [32 k][64 F] -> ws[F][k] ----
#pragma unroll
            for (int s = 0; s < 2; ++s) {
                const int kb = 4 * kg + 16 * s;
                const float u0 = W1[(size_t)(kc + kb + 0) * FDIM + fc + fcl];
                const float u1 = W1[(size_t)(kc + kb + 1) * FDIM + fc + fcl];
                const float u2 = W1[(size_t)(kc + kb + 2) * FDIM + fc + fcl];
                const float u3 = W1[(size_t)(kc + kb + 3) * FDIM + fc + fcl];
                _Float16 h0,l0,h1,l1,h2,l2,h3,l3;
                f2h2(u0,h0,l0); f2h2(u1,h1,l1); f2h2(u2,h2,l2); f2h2(u3,h3,l3);
                v4h hh, hl;
                hh[0]=h0; hh[1]=h1; hh[2]=h2; hh[3]=h3;
                hl[0]=l0; hl[1]=l1; hl[2]=l2; hl[3]=l3;
                *(v4h*)(ws_h + fcl * XST + kb) = hh;
                *(v4h*)(ws_l + fcl * XST + kb) = hl;
            }
            __syncthreads();
            // ---- MFMA 16x16x32 f16, 3 terms into one accumulator ----
            {
                v8h bh[2], bl[2];
#pragma unroll
                for (int nf = 0; nf < 2; ++nf) {
                    const int off = (32 * wc + 16 * nf + l15) * XST + 8 * l4;
                    bh[nf] = *(const v8h*)(ws_h + off);
                    bl[nf] = *(const v8h*)(ws_l + off);
                }
#pragma unroll
                for (int mf = 0; mf < 4; ++mf) {
                    const int off = (64 * wr + 16 * mf + l15) * XST + 8 * l4;
                    const v8h ah = *(const v8h*)(xs_h + off);
                    const v8h al = *(const v8h*)(xs_l + off);
#pragma unroll
                    for (int nf = 0; nf < 2; ++nf) {
                        acc[mf][nf] = __builtin_amdgcn_mfma_f32_16x16x32_f16(ah, bh[nf], acc[mf][nf], 0, 0, 0);
                        acc[mf][nf] = __builtin_amdgcn_mfma_f32_16x16x32_f16(al, bh[nf], acc[mf][nf], 0, 0, 0);
                        acc[mf][nf] = __builtin_amdgcn_mfma_f32_16x16x32_f16(ah, bl[nf], acc[mf][nf], 0, 0, 0);
                    }
                }
            }
        }
        __syncthreads();   // all MFMA xs/ws reads done; hs may alias them

        // ---- bias + exact GELU -> hs (f32) ----
        {
            float b1v[2];
#pragma unroll
            for (int nf = 0; nf < 2; ++nf)
                b1v[nf] = b1[fc + 32 * wc + 16 * nf + l15];
#pragma unroll
            for (int mf = 0; mf < 4; ++mf)
#pragma unroll
                for (int nf = 0; nf < 2; ++nf)
#pragma unroll
                    for (int r = 0; r < 4; ++r) {
                        const float v = acc[mf][nf][r] + b1v[nf];
                        const int tok  = 64 * wr + 16 * mf + 4 * l4 + r;
                        const int fcol = 32 * wc + 16 * nf + l15;
                        hs[tok * HST + fcol]
                            = 0.5f * v * (1.0f + erff(v * 0.70710678118654752f));
                    }
        }
        __syncthreads();

        // ---- GEMM2: direct per-expert dot; jb staggered by l4 so the four
        // 16-lane broadcast groups sit 16 banks apart (2-way = free, m136) ----
#pragma unroll
        for (int jb = 0; jb < 16; ++jb) {
            const int jbs = (jb + 4 * l4) & 15;
            float w2v[4];
#pragma unroll
            for (int j = 0; j < 4; ++j)
                w2v[j] = W2[(size_t)(fc + jbs * 4 + j) * EDIM + tx];
#pragma unroll
            for (int i = 0; i < 8; ++i) {
                const float4 hv = *(const float4*)(hs + (ty * 8 + i) * HST + jbs * 4);
                lg[i] = fmaf(hv.x, w2v[0], lg[i]);
                lg[i] = fmaf(hv.y, w2v[1], lg[i]);
                lg[i] = fmaf(hv.z, w2v[2], lg[i]);
                lg[i] = fmaf(hv.w, w2v[3], lg[i]);
            }
        }
        // next fc pass's first staging barrier protects hs
    }

    // ---- softmax + clip + top-2 + writes (R4-proven 16-lane butterflies) ----
#pragma unroll
    for (int i = 0; i < 8; ++i) {
        const int t = t0 + ty * 8 + i;
        float mx = lg[i];
#pragma unroll
        for (int m = 1; m < 16; m <<= 1) mx = fmaxf(mx, __shfl_xor(mx, m, 64));
        float p = expf(lg[i] - mx);
        float s = p;
#pragma unroll
        for (int m = 1; m < 16; m <<= 1) s += __shfl_xor(s, m, 64);
        float pr = p / s;
        pr = fminf(fmaxf(pr, 1e-9f), 1.0f - 1e-9f);

        float v1 = pr; int i1 = tx;
#pragma unroll
        for (int m = 1; m < 16; m <<= 1) {
            const float vo = __shfl_xor(v1, m, 64);
            const int   io = __shfl_xor(i1, m, 64);
            if (vo > v1 || (vo == v1 && io < i1)) { v1 = vo; i1 = io; }
        }
        float v2 = (tx == i1) ? -1.0f : pr; int i2 = tx;
#pragma unroll
        for (int m = 1; m < 16; m <<= 1) {
            const float vo = __shfl_xor(v2, m, 64);
            const int   io = __shfl_xor(i2, m, 64);
            if (vo > v2 || (vo == v2 && io < i2)) { v2 = vo; i2 = io; }
        }
        const float rs = 1.0f / (v1 + v2);

        float* om  = out + (size_t)t * EDIM;
        float* orp = out + (size_t)NTOK * 18 + (size_t)t * EDIM;
        float* opf = out + (size_t)NTOK * 34 + (size_t)t * EDIM;
        om[tx]  = (tx == i1 || tx == i2) ? 1.0f : 0.0f;
        orp[tx] = (tx == i1) ? v1 * rs : ((tx == i2) ? v2 * rs : 0.0f);
        opf[tx] = pr;
        if (tx == 0) {
            float2* oi = (float2*)(out + (size_t)NTOK * 16 + (size_t)t * 2);
            *oi = make_float2((float)i1, (float)i2);
        }
    }
}

extern "C" void kernel_launch(void* const* d_in, const int* in_sizes, int n_in,
                              void* d_out, int out_size, void* d_ws, size_t ws_size,
                              hipStream_t stream)
{
    const float* inp = (const float*)d_in[0];
    const float* cnd = (const float*)d_in[1];
    const float* W1  = (const float*)d_in[2];
    const float* b1  = (const float*)d_in[3];
    const float* W2  = (const float*)d_in[4];
    const float* b2  = (const float*)d_in[5];
    float* out = (float*)d_out;

    dim3 grid(NTOK / TBLK), block(256);
    hipLaunchKernelGGL(router_mfma7, grid, block, 0, stream,
                       inp, cnd, W1, b1, W2, b2, out);
}